// Round 7
// baseline (503.760 us; speedup 1.0000x reference)
//
#include <hip/hip_runtime.h>
#include <math.h>

typedef unsigned short u16;
typedef unsigned int u32;
typedef __bf16 b16x8 __attribute__((ext_vector_type(8)));
typedef float f32x4 __attribute__((ext_vector_type(4)));

#define BS 16
#define DSC 8
#define QL 512
#define DM 256
#define NH 16
#define DKH 16
#define DC 128
#define DFF 1024
#define S_TOT 4096
#define R_TOT 65536
#define ATT_SCALE 0.36067376022224085f  // 0.25 * log2(e)

static __device__ __forceinline__ u16 f2bf(float f) {
  u32 u = __float_as_uint(f);
  u += 0x7fffu + ((u >> 16) & 1u);   // RNE
  return (u16)(u >> 16);
}

static __device__ __forceinline__ uint4 pack8(float4 a, float4 b) {
  uint4 o;
  o.x = (u32)f2bf(a.x) | ((u32)f2bf(a.y) << 16);
  o.y = (u32)f2bf(a.z) | ((u32)f2bf(a.w) << 16);
  o.z = (u32)f2bf(b.x) | ((u32)f2bf(b.y) << 16);
  o.w = (u32)f2bf(b.z) | ((u32)f2bf(b.w) << 16);
  return o;
}

// async global->LDS DMA, 16B per lane; LDS dest is wave-uniform base + lane*16
static __device__ __forceinline__ void gload16(const u16* g, u16* l) {
  __builtin_amdgcn_global_load_lds(
      (const __attribute__((address_space(1))) void*)g,
      (__attribute__((address_space(3))) void*)l, 16, 0, 0);
}

// ---------------- f32 -> bf16 convert (vectorized, grid-stride) ----------------
__global__ void cvt_kernel(const float* __restrict__ in, u16* __restrict__ outp, int n4) {
  for (int i = blockIdx.x * blockDim.x + threadIdx.x; i < n4; i += gridDim.x * blockDim.x) {
    float4 v = *(const float4*)(in + (size_t)i * 4);
    uint2 o;
    o.x = (u32)f2bf(v.x) | ((u32)f2bf(v.y) << 16);
    o.y = (u32)f2bf(v.z) | ((u32)f2bf(v.w) << 16);
    *(uint2*)(outp + (size_t)i * 4) = o;
  }
}

// ---------------- out_w transpose (256x256 f32) ----------------
__global__ void transp_kernel(const float* __restrict__ w, float* __restrict__ wt) {
  int i = blockIdx.x * 256 + threadIdx.x;  // 65536
  int k = i >> 8, n = i & 255;
  wt[i] = w[n * 256 + k];
}

// ---------------- bf16 MFMA GEMM: C[M,N] = A[M,K] * B[N,K]^T (+epilogue) -------
// m97 recipe: 128x128 tile, BK=32, linear LDS [128][32] u16, staging via
// global_load_lds dwordx4 (no VGPR round-trip), 2 barriers/k-step, 16 KB LDS
// -> ~6 blocks/CU for cross-block latency hiding.
// 1-D grid, XCD-chunked swizzle: XCD x owns m-tiles [x*64, x*64+64), cycles the
// NTY column-tiles fastest so each A-tile stays L2-resident for all its columns.
// EPI: 0 = +bias -> bf16 out ; 1 = gelu(x+bias) -> bf16 out ; 2 = +bias+resid -> f32 out
// bf16 outputs staged through LDS for 16B/lane coalesced stores (kills the
// 1.7x write amplification measured in round 5).
template <int EPI, int NTY>
__global__ __launch_bounds__(256) void gemm_bf16(
    const u16* __restrict__ A, const u16* __restrict__ B,
    const float* __restrict__ bias, const float* __restrict__ resid,
    void* __restrict__ out, int K, int ldo) {
  __shared__ __align__(16) u16 smem[8192];  // As = [0,4096), Bs = [4096,8192)
  u16* As = smem;
  u16* Bs = smem + 4096;
  const int g = blockIdx.x;
  const int xcd = g & 7, tt = g >> 3;
  const int m0 = (xcd * 64 + tt / NTY) * 128;
  const int n0 = (tt % NTY) * 128;
  const int tid = threadIdx.x;
  const int w = tid >> 6, lane = tid & 63;
  const int wm = (w >> 1) * 64, wn = (w & 1) * 64;
  const int fr = lane & 15, fq = lane >> 4;

  f32x4 acc[4][4];
#pragma unroll
  for (int i = 0; i < 4; i++)
#pragma unroll
    for (int j = 0; j < 4; j++) acc[i][j] = (f32x4){0.f, 0.f, 0.f, 0.f};

  // staging: 8 groups of 16 rows per operand; wave w handles groups 2w, 2w+1.
  // lane -> (row = lane>>2, 16B col-chunk = lane&3) within a group.
  const int jr = lane >> 2, jc = (lane & 3) * 8;
  const u16* Ag = A + (size_t)m0 * K;
  const u16* Bg = B + (size_t)n0 * K;
  const u16* ga0 = Ag + (size_t)((2 * w) * 16 + jr) * K + jc;
  const u16* ga1 = Ag + (size_t)((2 * w + 1) * 16 + jr) * K + jc;
  const u16* gb0 = Bg + (size_t)((2 * w) * 16 + jr) * K + jc;
  const u16* gb1 = Bg + (size_t)((2 * w + 1) * 16 + jr) * K + jc;
  u16* la0 = As + (2 * w) * 512;      // group j occupies 512 u16 (16 rows x 32)
  u16* la1 = As + (2 * w + 1) * 512;
  u16* lb0 = Bs + (2 * w) * 512;
  u16* lb1 = Bs + (2 * w + 1) * 512;

  for (int k0 = 0; k0 < K; k0 += 32) {
    gload16(ga0 + k0, la0);
    gload16(ga1 + k0, la1);
    gload16(gb0 + k0, lb0);
    gload16(gb1 + k0, lb1);
    __syncthreads();  // drains LDS-DMA (vmcnt) + barrier

    uint4 af[4], bf[4];
#pragma unroll
    for (int i = 0; i < 4; i++) {
      af[i] = *(const uint4*)&As[(wm + i * 16 + fr) * 32 + fq * 8];
      bf[i] = *(const uint4*)&Bs[(wn + i * 16 + fr) * 32 + fq * 8];
    }
#pragma unroll
    for (int mi = 0; mi < 4; mi++)
#pragma unroll
      for (int ni = 0; ni < 4; ni++)
        acc[mi][ni] = __builtin_amdgcn_mfma_f32_16x16x32_bf16(
            __builtin_bit_cast(b16x8, af[mi]), __builtin_bit_cast(b16x8, bf[ni]),
            acc[mi][ni], 0, 0, 0);
    __syncthreads();
  }

  // epilogue. C/D layout: row = fq*4 + r, col = fr (per 16x16 frag).
  if (EPI == 2) {
    // f32 + resid direct: 16 lanes x 4B = 64B aligned segments, no amplification
#pragma unroll
    for (int ni = 0; ni < 4; ni++) {
      const int gc = n0 + wn + ni * 16 + fr;
      const float bv = bias[gc];
#pragma unroll
      for (int mi = 0; mi < 4; mi++) {
#pragma unroll
        for (int r = 0; r < 4; r++) {
          const int gr = m0 + wm + mi * 16 + fq * 4 + r;
          float v = acc[mi][ni][r] + bv + resid[(size_t)gr * ldo + gc];
          ((float*)out)[(size_t)gr * ldo + gc] = v;
        }
      }
    }
  } else {
    // bf16 out: stage 64-row halves in LDS, store 16B/lane coalesced rows
#pragma unroll
    for (int h = 0; h < 2; h++) {
      if ((w >> 1) == h) {
#pragma unroll
        for (int ni = 0; ni < 4; ni++) {
          const float bv = bias[n0 + wn + ni * 16 + fr];
#pragma unroll
          for (int mi = 0; mi < 4; mi++) {
#pragma unroll
            for (int r = 0; r < 4; r++) {
              float v = acc[mi][ni][r] + bv;
              if (EPI == 1) v = 0.5f * v * (1.f + erff(v * 0.70710678118f));
              smem[(mi * 16 + fq * 4 + r) * 128 + wn + ni * 16 + fr] = f2bf(v);
            }
          }
        }
      }
      __syncthreads();
#pragma unroll
      for (int cc = 0; cc < 4; cc++) {
        const int idx = tid + cc * 256;       // 1024 chunks = 64 rows x 16
        const int row = idx >> 4, c16 = idx & 15;
        uint4 v = *(const uint4*)&smem[row * 128 + c16 * 8];
        *(uint4*)((u16*)out + (size_t)(m0 + h * 64 + row) * ldo + n0 + c16 * 8) = v;
      }
      __syncthreads();
    }
  }
}

// ---------------- MFMA flash attention ----------------------------------------
// Block = (b, h, c-half): 64 router rows vs all 4096 s. 4 waves over disjoint
// 32-s tiles, per-wave private LDS -> no barrier in main loop.
__global__ __launch_bounds__(256) void attn_mfma(const u16* __restrict__ kbf,
                                                 const float* __restrict__ router,
                                                 float* __restrict__ ctxb) {
  const int blk = blockIdx.x;
  const int bh = blk >> 1, chalf = blk & 1;
  const int b = bh >> 4, h = bh & 15;
  const int tid = threadIdx.x, w = tid >> 6, lane = tid & 63;
  const int l15 = lane & 15, lg = lane >> 4;

  __shared__ __align__(16) u16 Pl[4][64 * 40];   // per-wave P[c][s0..31] pad40
  __shared__ __align__(16) u16 kTl[4][16 * 40];  // per-wave k^T[d][s0..31] pad40
  __shared__ float ctxp[4][64][16];
  __shared__ float lp[4][64];

  // router B-frags (N=c, K=d zero-padded 16->32), scale folded (0.25*log2e)
  uint4 rB[4];
  {
    const float* rb = router + ((size_t)h * DC + chalf * 64) * 16;
#pragma unroll
    for (int nf = 0; nf < 4; nf++) {
      if (lg < 2) {
        const float* p = rb + (nf * 16 + l15) * 16 + lg * 8;
        float4 lo = *(const float4*)p;
        float4 hi = *(const float4*)(p + 4);
        lo.x *= ATT_SCALE; lo.y *= ATT_SCALE; lo.z *= ATT_SCALE; lo.w *= ATT_SCALE;
        hi.x *= ATT_SCALE; hi.y *= ATT_SCALE; hi.z *= ATT_SCALE; hi.w *= ATT_SCALE;
        rB[nf] = pack8(lo, hi);
      } else {
        rB[nf] = make_uint4(0, 0, 0, 0);
      }
    }
  }

  const u16* kg = kbf + (size_t)b * S_TOT * (NH * DKH) + h * 16;  // row stride 256

  f32x4 ctx[4];
#pragma unroll
  for (int i = 0; i < 4; i++) ctx[i] = (f32x4){0.f, 0.f, 0.f, 0.f};
  float ladd[4] = {0.f, 0.f, 0.f, 0.f};

  for (int tt = w; tt < 128; tt += 4) {
    const int s0 = tt * 32;
    uint4 kA[2];
#pragma unroll
    for (int mf = 0; mf < 2; mf++)
      kA[mf] = (lg < 2)
                   ? *(const uint4*)(kg + (size_t)(s0 + mf * 16 + l15) * 256 + lg * 8)
                   : make_uint4(0, 0, 0, 0);
    {
      const int sl = lane & 31, dh = lane >> 5;
      uint4 kv = *(const uint4*)(kg + (size_t)(s0 + sl) * 256 + dh * 8);
      const u16* pv = (const u16*)&kv;
#pragma unroll
      for (int jj = 0; jj < 8; jj++) kTl[w][(dh * 8 + jj) * 40 + sl] = pv[jj];
    }
    f32x4 sc[2][4];
#pragma unroll
    for (int mf = 0; mf < 2; mf++)
#pragma unroll
      for (int nf = 0; nf < 4; nf++)
        sc[mf][nf] = __builtin_amdgcn_mfma_f32_16x16x32_bf16(
            __builtin_bit_cast(b16x8, kA[mf]), __builtin_bit_cast(b16x8, rB[nf]),
            (f32x4){0.f, 0.f, 0.f, 0.f}, 0, 0, 0);
#pragma unroll
    for (int mf = 0; mf < 2; mf++)
#pragma unroll
      for (int nf = 0; nf < 4; nf++) {
        float p0 = exp2f(sc[mf][nf][0]);
        float p1 = exp2f(sc[mf][nf][1]);
        float p2 = exp2f(sc[mf][nf][2]);
        float p3 = exp2f(sc[mf][nf][3]);
        ladd[nf] += (p0 + p1) + (p2 + p3);
        uint2 pk;
        pk.x = (__float_as_uint(p0) >> 16) | (__float_as_uint(p1) & 0xffff0000u);
        pk.y = (__float_as_uint(p2) >> 16) | (__float_as_uint(p3) & 0xffff0000u);
        *(uint2*)&Pl[w][(nf * 16 + l15) * 40 + mf * 16 + lg * 4] = pk;
      }
    uint4 kB = *(const uint4*)&kTl[w][l15 * 40 + lg * 8];
#pragma unroll
    for (int mfc = 0; mfc < 4; mfc++) {
      uint4 pA = *(const uint4*)&Pl[w][(mfc * 16 + l15) * 40 + lg * 8];
      ctx[mfc] = __builtin_amdgcn_mfma_f32_16x16x32_bf16(
          __builtin_bit_cast(b16x8, pA), __builtin_bit_cast(b16x8, kB), ctx[mfc],
          0, 0, 0);
    }
  }

#pragma unroll
  for (int nf = 0; nf < 4; nf++) {
    float v = ladd[nf];
    v += __shfl_xor(v, 16);
    v += __shfl_xor(v, 32);
    ladd[nf] = v;
  }
  if (lane < 16) {
#pragma unroll
    for (int nf = 0; nf < 4; nf++) lp[w][nf * 16 + lane] = ladd[nf];
  }
#pragma unroll
  for (int mfc = 0; mfc < 4; mfc++)
#pragma unroll
    for (int r = 0; r < 4; r++) ctxp[w][mfc * 16 + lg * 4 + r][l15] = ctx[mfc][r];
  __syncthreads();
#pragma unroll
  for (int i = 0; i < 4; i++) {
    const int idx = tid + i * 256;
    const int c = idx >> 4, d = idx & 15;
    const float L = lp[0][c] + lp[1][c] + lp[2][c] + lp[3][c];
    const float V = ctxp[0][c][d] + ctxp[1][c][d] + ctxp[2][c][d] + ctxp[3][c][d];
    ctxb[((size_t)b * DC + chalf * 64 + c) * (NH * DKH) + h * 16 + d] = V / L;
  }
}

// ---------------- ar[b,c,:] = ctx[b,c,:] @ out_w^T + out_b + pos_embd[c,:] -----
__global__ __launch_bounds__(256) void ar_kernel(const float* __restrict__ ctxb,
                                                 const float* __restrict__ owT,
                                                 const float* __restrict__ ob,
                                                 const float* __restrict__ pos,
                                                 float* __restrict__ ar) {
  const int b = blockIdx.x, g = blockIdx.y, n = threadIdx.x;
  __shared__ float cl[8][256];
#pragma unroll
  for (int j = 0; j < 8; j++)
    cl[j][n] = ctxb[((size_t)b * DC + g * 8 + j) * 256 + n];
  __syncthreads();
  float acc[8];
#pragma unroll
  for (int j = 0; j < 8; j++) acc[j] = ob[n] + pos[(size_t)(g * 8 + j) * 256 + n];
  for (int k = 0; k < 256; k++) {
    float wv = owT[(size_t)k * 256 + n];
#pragma unroll
    for (int j = 0; j < 8; j++) acc[j] += cl[j][k] * wv;
  }
#pragma unroll
  for (int j = 0; j < 8; j++) ar[((size_t)b * DC + g * 8 + j) * 256 + n] = acc[j];
}

// ---------------- t[b,q,:] = sum_c m_expand[q,c] * ar[b,c,:] -------------------
__global__ __launch_bounds__(256) void texp_kernel(const float* __restrict__ me,
                                                   const float* __restrict__ ar,
                                                   float* __restrict__ tb) {
  const int b = blockIdx.x, qg = blockIdx.y, d = threadIdx.x;
  __shared__ float ml[16][128];
  const int q0 = qg * 16;
  for (int i = threadIdx.x; i < 16 * 128; i += 256) {
    int qq = i >> 7, c = i & 127;
    ml[qq][c] = me[(size_t)(q0 + qq) * 128 + c];
  }
  __syncthreads();
  float acc[16];
#pragma unroll
  for (int qq = 0; qq < 16; qq++) acc[qq] = 0.f;
  for (int c = 0; c < 128; c++) {
    float v = ar[((size_t)b * DC + c) * 256 + d];
#pragma unroll
    for (int qq = 0; qq < 16; qq++) acc[qq] += ml[qq][c] * v;
  }
#pragma unroll
  for (int qq = 0; qq < 16; qq++)
    tb[((size_t)(b * QL + q0 + qq)) * 256 + d] = acc[qq];
}

// ---------------- LN1: y = LN(src + scale_tf[x]*t) ; f32 y -> d_out, bf16 -> ws -
__global__ __launch_bounds__(256) void ln1_kernel(
    const float* __restrict__ src, const float* __restrict__ tbuf,
    const float* __restrict__ stf, const float* __restrict__ g,
    const float* __restrict__ bb, float* __restrict__ yout, u16* __restrict__ ybf) {
  const int w = threadIdx.x >> 6, lane = threadIdx.x & 63;
  const int r = blockIdx.x * 4 + w;
  const int b = r >> 12, x = (r >> 9) & 7, q = r & 511;
  const size_t base = (size_t)r * DM + lane * 4;
  float4 s4 = *(const float4*)(src + base);
  float4 t4 = *(const float4*)(tbuf + ((size_t)(b * QL + q) * DM + lane * 4));
  const float sc = stf[x];
  float v0 = s4.x + sc * t4.x, v1 = s4.y + sc * t4.y;
  float v2 = s4.z + sc * t4.z, v3 = s4.w + sc * t4.w;
  float sum = v0 + v1 + v2 + v3;
  float sq = v0 * v0 + v1 * v1 + v2 * v2 + v3 * v3;
#pragma unroll
  for (int off = 32; off; off >>= 1) {
    sum += __shfl_xor(sum, off);
    sq += __shfl_xor(sq, off);
  }
  const float mean = sum * (1.f / DM);
  const float var = sq * (1.f / DM) - mean * mean;
  const float rs = rsqrtf(var + 1e-5f);
  float4 gv = *(const float4*)(g + lane * 4);
  float4 bv = *(const float4*)(bb + lane * 4);
  float o0 = (v0 - mean) * rs * gv.x + bv.x;
  float o1 = (v1 - mean) * rs * gv.y + bv.y;
  float o2 = (v2 - mean) * rs * gv.z + bv.z;
  float o3 = (v3 - mean) * rs * gv.w + bv.w;
  float4 o = {o0, o1, o2, o3};
  *(float4*)(yout + base) = o;
  uint2 p;
  p.x = (u32)f2bf(o0) | ((u32)f2bf(o1) << 16);
  p.y = (u32)f2bf(o2) | ((u32)f2bf(o3) << 16);
  *(uint2*)(ybf + base) = p;
}

// ---------------- LN2: in-place on d_out --------------------------------------
__global__ __launch_bounds__(256) void ln2_kernel(float* __restrict__ io,
                                                  const float* __restrict__ g,
                                                  const float* __restrict__ bb) {
  const int w = threadIdx.x >> 6, lane = threadIdx.x & 63;
  const int r = blockIdx.x * 4 + w;
  const size_t base = (size_t)r * DM + lane * 4;
  float4 v4 = *(const float4*)(io + base);
  float sum = v4.x + v4.y + v4.z + v4.w;
  float sq = v4.x * v4.x + v4.y * v4.y + v4.z * v4.z + v4.w * v4.w;
#pragma unroll
  for (int off = 32; off; off >>= 1) {
    sum += __shfl_xor(sum, off);
    sq += __shfl_xor(sq, off);
  }
  const float mean = sum * (1.f / DM);
  const float var = sq * (1.f / DM) - mean * mean;
  const float rs = rsqrtf(var + 1e-5f);
  float4 gv = *(const float4*)(g + lane * 4);
  float4 bv = *(const float4*)(bb + lane * 4);
  float4 o;
  o.x = (v4.x - mean) * rs * gv.x + bv.x;
  o.y = (v4.y - mean) * rs * gv.y + bv.y;
  o.z = (v4.z - mean) * rs * gv.z + bv.z;
  o.w = (v4.w - mean) * rs * gv.w + bv.w;
  *(float4*)(io + base) = o;
}

extern "C" void kernel_launch(void* const* d_in, const int* in_sizes, int n_in,
                              void* d_out, int out_size, void* d_ws, size_t ws_size,
                              hipStream_t stream) {
  const float* src = (const float*)d_in[0];
  const float* router = (const float*)d_in[1];
  const float* wk_w = (const float*)d_in[2];
  const float* wk_b = (const float*)d_in[3];
  const float* out_w = (const float*)d_in[4];
  const float* out_b = (const float*)d_in[5];
  const float* m_exp = (const float*)d_in[6];
  const float* pos = (const float*)d_in[7];
  const float* stf = (const float*)d_in[8];
  const float* ln1g = (const float*)d_in[9];
  const float* ln1b = (const float*)d_in[10];
  const float* f1w = (const float*)d_in[11];
  const float* f1b = (const float*)d_in[12];
  const float* f2w = (const float*)d_in[13];
  const float* f2b = (const float*)d_in[14];
  const float* ln2g = (const float*)d_in[15];
  const float* ln2b = (const float*)d_in[16];
  float* out = (float*)d_out;

  unsigned char* ws = (unsigned char*)d_ws;
  // h_bf [0,128M) aliases src_bf [0,32M): src_bf dead after kproj, h written by FFN1
  u16* h_bf = (u16*)(ws + 0);               // 134,217,728 B
  u16* src_bf = (u16*)(ws + 0);             // 33,554,432 B (aliased, dead after kproj)
  u16* y_bf = (u16*)(ws + 134217728);       // 33,554,432 B
  u16* k_bf = (u16*)(ws + 167772160);       // 33,554,432 B
  u16* wkw_bf = (u16*)(ws + 201326592);     // 131,072 B
  u16* f1w_bf = (u16*)(ws + 201457664);     // 524,288 B
  u16* f2w_bf = (u16*)(ws + 201981952);     // 524,288 B
  float* owT = (float*)(ws + 202506240);    // 262,144 B
  float* ctxb = (float*)(ws + 202768384);   // 2,097,152 B
  float* arb = (float*)(ws + 204865536);    // 2,097,152 B
  float* tb = (float*)(ws + 206962688);     // 8,388,608 B  (total 215,351,296 B)

  cvt_kernel<<<2048, 256, 0, stream>>>(src, src_bf, R_TOT * DM / 4);
  cvt_kernel<<<64, 256, 0, stream>>>(wk_w, wkw_bf, 256 * 256 / 4);
  cvt_kernel<<<256, 256, 0, stream>>>(f1w, f1w_bf, DFF * DM / 4);
  cvt_kernel<<<256, 256, 0, stream>>>(f2w, f2w_bf, DM * DFF / 4);
  transp_kernel<<<256, 256, 0, stream>>>(out_w, owT);

  // K-projection: k = src @ Wk_w^T + Wk_b  (bf16 out [b*S][h*16+d])
  gemm_bf16<0, 2><<<1024, 256, 0, stream>>>(src_bf, wkw_bf, wk_b, nullptr,
                                            k_bf, DM, DM);
  attn_mfma<<<512, 256, 0, stream>>>(k_bf, router, ctxb);
  ar_kernel<<<dim3(16, 16), 256, 0, stream>>>(ctxb, owT, out_b, pos, arb);
  texp_kernel<<<dim3(16, 32), 256, 0, stream>>>(m_exp, arb, tb);
  ln1_kernel<<<16384, 256, 0, stream>>>(src, tb, stf, ln1g, ln1b, out, y_bf);

  // FFN1: h = gelu(y @ ff1_w^T + b1)  (bf16 h in ws)
  gemm_bf16<1, 8><<<4096, 256, 0, stream>>>(y_bf, f1w_bf, f1b, nullptr,
                                            h_bf, DM, DFF);
  // FFN2: pre-LN2 = y + h @ ff2_w^T + b2  (f32, in-place on d_out)
  gemm_bf16<2, 2><<<1024, 256, 0, stream>>>(h_bf, f2w_bf, f2b, out,
                                            out, DFF, DM);
  ln2_kernel<<<16384, 256, 0, stream>>>(out, ln2g, ln2b);
}